// Round 5
// baseline (344.886 us; speedup 1.0000x reference)
//
#include <hip/hip_runtime.h>
#include <math.h>

#define NEG_SLOPE 0.2f

typedef __attribute__((ext_vector_type(8))) short short8;
typedef __attribute__((ext_vector_type(4))) float f32x4;

__device__ __forceinline__ float leaky(float x) { return x > 0.f ? x : NEG_SLOPE * x; }

// fp32 -> bf16 (RNE)
__device__ __forceinline__ short f2bf(float f) {
    union { float f; unsigned u; } v; v.f = f;
    unsigned r = v.u + 0x7fffu + ((v.u >> 16) & 1u);
    return (short)(r >> 16);
}
__device__ __forceinline__ float bf2f(unsigned short s) {
    union { unsigned u; float f; } v; v.u = ((unsigned)s) << 16;
    return v.f;
}

// ================= CSR build: workgroup-exclusive counting sort =================
// bucket = dst >> 7 (128 nodes per bucket). Each (bucket, chunk) pair gets an
// exclusive contiguous output range -> no cross-XCD cacheline sharing.
// pairbuf entries are packed (src << 7) | (dst & 127): src < 2^17, halves traffic.
#define GCHUNK 256
#define NB_MAX 1024   // supports N <= 131072

__global__ __launch_bounds__(256) void hist_kernel(const int* __restrict__ dst, int E, int nbuck,
                                                   int* __restrict__ histG, int* __restrict__ total) {
    __shared__ int lh[NB_MAX];
    int g = blockIdx.x, t = threadIdx.x;
    for (int i = t; i < nbuck; i += 256) lh[i] = 0;
    __syncthreads();
    int ce = (E + GCHUNK - 1) / GCHUNK;
    int e0 = g * ce, e1 = min(e0 + ce, E);
    for (int e = e0 + t; e < e1; e += 256)
        atomicAdd(&lh[dst[e] >> 7], 1);
    __syncthreads();
    for (int i = t; i < nbuck; i += 256) {
        histG[i * GCHUNK + g] = lh[i];
        if (lh[i]) atomicAdd(&total[i], lh[i]);
    }
}

__global__ __launch_bounds__(1024) void bscan_kernel(const int* __restrict__ total,
                                                     int* __restrict__ bbase, int nbuck) {
    __shared__ int sh[1024];
    int t = threadIdx.x;
    int v = (t < nbuck) ? total[t] : 0;
    sh[t] = v; __syncthreads();
    for (int s = 1; s < 1024; s <<= 1) {
        int add = (t >= s) ? sh[t - s] : 0;
        __syncthreads();
        sh[t] += add;
        __syncthreads();
    }
    if (t < nbuck) bbase[t] = sh[t] - v;
    if (t == nbuck - 1) bbase[nbuck] = sh[t];
}

__global__ __launch_bounds__(256) void bstart_kernel(const int* __restrict__ histG,
                                                     const int* __restrict__ bbase,
                                                     int* __restrict__ startG, int nbuck) {
    __shared__ int sh[256];
    int b = blockIdx.x, t = threadIdx.x;
    int v = histG[b * GCHUNK + t];
    sh[t] = v; __syncthreads();
    for (int s = 1; s < 256; s <<= 1) {
        int add = (t >= s) ? sh[t - s] : 0;
        __syncthreads();
        sh[t] += add;
        __syncthreads();
    }
    startG[b * GCHUNK + t] = bbase[b] + sh[t] - v;
}

__global__ __launch_bounds__(256) void bucket_scatter(const int* __restrict__ src,
                                                      const int* __restrict__ dst, int E, int nbuck,
                                                      const int* __restrict__ startG,
                                                      int* __restrict__ pairbuf) {
    __shared__ int cur[NB_MAX];
    int g = blockIdx.x, t = threadIdx.x;
    for (int i = t; i < nbuck; i += 256) cur[i] = startG[i * GCHUNK + g];
    __syncthreads();
    int ce = (E + GCHUNK - 1) / GCHUNK;
    int e0 = g * ce, e1 = min(e0 + ce, E);
    for (int e = e0 + t; e < e1; e += 256) {
        int d = dst[e], b = d >> 7;
        int pos = atomicAdd(&cur[b], 1);
        pairbuf[pos] = (src[e] << 7) | (d & 127);
    }
}

__global__ __launch_bounds__(256) void bucket_place(const int* __restrict__ pairbuf,
                                                    const int* __restrict__ bbase, int nbuck, int N,
                                                    int* __restrict__ deg, int* __restrict__ off,
                                                    int* __restrict__ csr) {
    __shared__ int stash[4096];
    __shared__ int ldeg[128], lcur[128], sh[128];
    int b = blockIdx.x, t = threadIdx.x;
    int p0 = bbase[b], p1 = bbase[b + 1];
    int cnt = p1 - p0;
    int node0 = b << 7;
    for (int i = t; i < 128; i += 256) ldeg[i] = 0;
    __syncthreads();
    for (int i = t; i < cnt; i += 256) {
        int pr = pairbuf[p0 + i];
        if (i < 4096) stash[i] = pr;
        atomicAdd(&ldeg[pr & 127], 1);
    }
    __syncthreads();
    if (t < 128) sh[t] = ldeg[t];
    __syncthreads();
    for (int s = 1; s < 128; s <<= 1) {
        int add = (t >= s && t < 128) ? sh[t - s] : 0;
        __syncthreads();
        if (t < 128) sh[t] += add;
        __syncthreads();
    }
    if (t < 128) {
        int excl = sh[t] - ldeg[t];
        int n = node0 + t;
        if (n < N) { deg[n] = ldeg[t]; off[n] = p0 + excl; }
        lcur[t] = p0 + excl;
    }
    __syncthreads();
    for (int i = t; i < cnt; i += 256) {
        int pr = (i < 4096) ? stash[i] : pairbuf[p0 + i];
        int pos = atomicAdd(&lcur[pr & 127], 1);
        csr[pos] = ((unsigned)pr) >> 7;
    }
}

// ---------------- GEMM1 (MFMA): h1 = bf16(x @ W1), dots in fp32 ----------------
__global__ __launch_bounds__(256) void gemm1_mfma(
    const float* __restrict__ x, const float* __restrict__ W1,
    const float* __restrict__ att_src, const float* __restrict__ att_dst,
    unsigned short* __restrict__ h1, float* __restrict__ a_src, float* __restrict__ a_dst, int N)
{
    __shared__ short Bl[16 * 64 * 8];   // 16 B-frags (ct,s), 16 KB
    __shared__ float Cs[4][32 * 64];    // fp32 C stage, 32 KB
    int tid = threadIdx.x;
    for (int f0 = tid; f0 < 1024; f0 += 256) {
        int lane = f0 & 63, s = (f0 >> 6) & 3, ct = f0 >> 8;
        int kb = s * 32 + ((lane >> 4) << 3);
        int col = ct * 16 + (lane & 15);
        short* dp = &Bl[f0 * 8];
#pragma unroll
        for (int j = 0; j < 8; ++j) dp[j] = f2bf(W1[(kb + j) * 64 + col]);
    }
    __syncthreads();

    int lane = tid & 63, w = tid >> 6;
    int row0 = blockIdx.x * 128 + w * 32;
    int ra = min(row0 + (lane & 15), N - 1);
    int rb = min(row0 + 16 + (lane & 15), N - 1);
    const float* pa = x + (size_t)ra * 128 + ((lane >> 4) << 3);
    const float* pb = x + (size_t)rb * 128 + ((lane >> 4) << 3);

    f32x4 acc[2][4];
#pragma unroll
    for (int i = 0; i < 2; ++i)
#pragma unroll
        for (int j = 0; j < 4; ++j) acc[i][j] = (f32x4){0.f, 0.f, 0.f, 0.f};

#pragma unroll
    for (int s = 0; s < 4; ++s) {
        float4 a0 = *(const float4*)(pa + s * 32);
        float4 a1 = *(const float4*)(pa + s * 32 + 4);
        float4 c0 = *(const float4*)(pb + s * 32);
        float4 c1 = *(const float4*)(pb + s * 32 + 4);
        short8 af, cf;
        af[0] = f2bf(a0.x); af[1] = f2bf(a0.y); af[2] = f2bf(a0.z); af[3] = f2bf(a0.w);
        af[4] = f2bf(a1.x); af[5] = f2bf(a1.y); af[6] = f2bf(a1.z); af[7] = f2bf(a1.w);
        cf[0] = f2bf(c0.x); cf[1] = f2bf(c0.y); cf[2] = f2bf(c0.z); cf[3] = f2bf(c0.w);
        cf[4] = f2bf(c1.x); cf[5] = f2bf(c1.y); cf[6] = f2bf(c1.z); cf[7] = f2bf(c1.w);
#pragma unroll
        for (int ct = 0; ct < 4; ++ct) {
            short8 wf = *(const short8*)&Bl[((ct * 4 + s) * 64 + lane) * 8];
            acc[0][ct] = __builtin_amdgcn_mfma_f32_16x16x32_bf16(af, wf, acc[0][ct], 0, 0, 0);
            acc[1][ct] = __builtin_amdgcn_mfma_f32_16x16x32_bf16(cf, wf, acc[1][ct], 0, 0, 0);
        }
    }

    float* cs = &Cs[w][0];
#pragma unroll
    for (int rt = 0; rt < 2; ++rt)
#pragma unroll
        for (int ct = 0; ct < 4; ++ct)
#pragma unroll
            for (int r = 0; r < 4; ++r) {
                int row = rt * 16 + ((lane >> 4) << 2) + r;
                int col = ct * 16 + (lane & 15);
                cs[row * 64 + col] = acc[rt][ct][r];
            }
    __syncthreads();

    float asv = att_src[lane], adv = att_dst[lane];
    for (int r = 0; r < 32; ++r) {
        int row = row0 + r;
        float v = cs[r * 64 + lane];
        float ts = v * asv, td = v * adv;
        ts += __shfl_xor(ts, 1); ts += __shfl_xor(ts, 2); ts += __shfl_xor(ts, 4);
        td += __shfl_xor(td, 1); td += __shfl_xor(td, 2); td += __shfl_xor(td, 4);
        if (row < N) {
            h1[(size_t)row * 64 + lane] = (unsigned short)f2bf(v);
            if ((lane & 7) == 0) {
                a_src[row * 8 + (lane >> 3)] = ts;
                a_dst[row * 8 + (lane >> 3)] = td;
            }
        }
    }
}

// ---------------- layer-1 aggregate (bf16 h1, batched gathers) ----------------
__global__ __launch_bounds__(256) void agg1_kernel(
    const unsigned short* __restrict__ h1, const float* __restrict__ a_src, const float* __restrict__ a_dst,
    const int* __restrict__ off, const int* __restrict__ deg, const int* __restrict__ csr,
    const float* __restrict__ b1, unsigned short* __restrict__ helu, int N)
{
    int n = (blockIdx.x * 256 + threadIdx.x) >> 6;
    int lane = threadIdx.x & 63;
    if (n >= N) return;
    int o = off[n], d = deg[n];
    int h8 = lane & 7, g = lane >> 3, hf = lane >> 3;

    float adst = a_dst[n * 8 + h8];
    float pself = __expf(leaky(a_src[n * 8 + h8] + adst));
    float s = (g == 0) ? pself : 0.f;
    float acc0 = __shfl(pself, hf) * bf2f(h1[(size_t)n * 64 + lane]);
    float acc1 = 0.f;

    for (int base = 0; base < d; base += 64) {
        int idx = base + lane;
        int sv = (idx < d) ? csr[o + idx] : 0;
        int lim = min(64, d - base);
        int tmax = (lim + 7) >> 3;
        for (int t = 0; t < tmax; ++t) {
            int eidx = t * 8 + g;
            int srcn_a = __shfl(sv, eidx);
            float p = 0.f;
            if (eidx < lim) p = __expf(leaky(a_src[srcn_a * 8 + h8] + adst));
            s += p;
#pragma unroll
            for (int j = 0; j < 8; j += 2) {
                int sA = __shfl(sv, t * 8 + j);
                int sB = __shfl(sv, t * 8 + j + 1);
                float aA = __shfl(p, j * 8 + hf);
                float aB = __shfl(p, (j + 1) * 8 + hf);
                acc0 = fmaf(aA, bf2f(h1[(size_t)sA * 64 + lane]), acc0);
                acc1 = fmaf(aB, bf2f(h1[(size_t)sB * 64 + lane]), acc1);
            }
        }
    }
    s += __shfl_xor(s, 8); s += __shfl_xor(s, 16); s += __shfl_xor(s, 32);
    float sf = __shfl(s, hf);
    float v = (acc0 + acc1) / sf + b1[lane];
    helu[(size_t)n * 64 + lane] = (unsigned short)f2bf((v > 0.f) ? v : (__expf(v) - 1.f));
}

// -------- GEMM2 (MFMA): h2p = bf16(helu @ W2), rows PADDED to 64 cols --------
// cols 40..63 of the C-stage are zero (B frags zero-padded), so storing all 64
// lanes produces a zero-padded, 128B-aligned row -> agg2 gathers 1 line/edge.
__global__ __launch_bounds__(256) void gemm2_mfma(
    const unsigned short* __restrict__ hin, const float* __restrict__ W2,
    const float* __restrict__ att_src2, const float* __restrict__ att_dst2,
    unsigned short* __restrict__ h2p, float* __restrict__ a_src, float* __restrict__ a_dst, int N)
{
    __shared__ short Bl[6 * 64 * 8];
    __shared__ float Cs[4][32 * 48];
    int tid = threadIdx.x;
    for (int f0 = tid; f0 < 384; f0 += 256) {
        int lane = f0 & 63; int fr = f0 >> 6; int s = fr & 1, ct = fr >> 1;
        int kb = s * 32 + ((lane >> 4) << 3);
        int col = ct * 16 + (lane & 15);
        short* dp = &Bl[f0 * 8];
#pragma unroll
        for (int j = 0; j < 8; ++j) dp[j] = (col < 40) ? f2bf(W2[(kb + j) * 40 + col]) : (short)0;
    }
    __syncthreads();

    int lane = tid & 63, w = tid >> 6;
    int row0 = blockIdx.x * 128 + w * 32;
    int ra = min(row0 + (lane & 15), N - 1);
    int rb = min(row0 + 16 + (lane & 15), N - 1);
    const unsigned short* pa = hin + (size_t)ra * 64 + ((lane >> 4) << 3);
    const unsigned short* pb = hin + (size_t)rb * 64 + ((lane >> 4) << 3);

    f32x4 acc[2][3];
#pragma unroll
    for (int i = 0; i < 2; ++i)
#pragma unroll
        for (int j = 0; j < 3; ++j) acc[i][j] = (f32x4){0.f, 0.f, 0.f, 0.f};

#pragma unroll
    for (int s = 0; s < 2; ++s) {
        short8 af = *(const short8*)(pa + s * 32);
        short8 cf = *(const short8*)(pb + s * 32);
#pragma unroll
        for (int ct = 0; ct < 3; ++ct) {
            short8 wf = *(const short8*)&Bl[((ct * 2 + s) * 64 + lane) * 8];
            acc[0][ct] = __builtin_amdgcn_mfma_f32_16x16x32_bf16(af, wf, acc[0][ct], 0, 0, 0);
            acc[1][ct] = __builtin_amdgcn_mfma_f32_16x16x32_bf16(cf, wf, acc[1][ct], 0, 0, 0);
        }
    }

    float* cs = &Cs[w][0];
#pragma unroll
    for (int rt = 0; rt < 2; ++rt)
#pragma unroll
        for (int ct = 0; ct < 3; ++ct)
#pragma unroll
            for (int r = 0; r < 4; ++r) {
                int row = rt * 16 + ((lane >> 4) << 2) + r;
                int col = ct * 16 + (lane & 15);
                cs[row * 48 + col] = acc[rt][ct][r];
            }
    __syncthreads();

    float asv = (lane < 40) ? att_src2[lane] : 0.f;
    float adv = (lane < 40) ? att_dst2[lane] : 0.f;
    for (int r = 0; r < 32; ++r) {
        int row = row0 + r;
        float v = (lane < 48) ? cs[r * 48 + lane] : 0.f;   // cols 40..47 are zero; 48+ zero
        float ts = (lane < 40) ? v * asv : 0.f;
        float td = (lane < 40) ? v * adv : 0.f;
        for (int st = 1; st < 64; st <<= 1) { ts += __shfl_xor(ts, st); td += __shfl_xor(td, st); }
        if (row < N) {
            h2p[(size_t)row * 64 + lane] = (unsigned short)f2bf(v);  // padded row
            if (lane == 0) { a_src[row] = ts; a_dst[row] = td; }
        }
    }
}

// ---------------- layer-2 aggregate + bias + log_softmax (padded bf16 h2p) ----------------
__global__ __launch_bounds__(256) void agg2_kernel(
    const unsigned short* __restrict__ h2p, const float* __restrict__ a_src, const float* __restrict__ a_dst,
    const int* __restrict__ off, const int* __restrict__ deg, const int* __restrict__ csr,
    const float* __restrict__ b2, float* __restrict__ out, int N)
{
    int n = (blockIdx.x * 256 + threadIdx.x) >> 6;
    int lane = threadIdx.x & 63;
    if (n >= N) return;
    int o = off[n], d = deg[n];

    float adst = a_dst[n];
    float pself = __expf(leaky(a_src[n] + adst));
    float acc0 = pself * bf2f(h2p[(size_t)n * 64 + lane]);
    float acc1 = 0.f;
    float sp = 0.f;

    for (int base = 0; base < d; base += 64) {
        int idx = base + lane;
        int sv = (idx < d) ? csr[o + idx] : 0;
        float pv = 0.f;
        if (idx < d) pv = __expf(leaky(a_src[sv] + adst));
        sp += pv;
        int lim = min(64, d - base);
        for (int j = 0; j < lim; j += 4) {
#pragma unroll
            for (int u = 0; u < 4; u += 2) {
                int sA = __shfl(sv, j + u);
                int sB = __shfl(sv, j + u + 1);
                float aA = (j + u < lim) ? __shfl(pv, j + u) : 0.f;
                float aB = (j + u + 1 < lim) ? __shfl(pv, j + u + 1) : 0.f;
                acc0 = fmaf(aA, bf2f(h2p[(size_t)sA * 64 + lane]), acc0);
                acc1 = fmaf(aB, bf2f(h2p[(size_t)sB * 64 + lane]), acc1);
            }
        }
    }
    for (int st = 1; st < 64; st <<= 1) sp += __shfl_xor(sp, st);
    float stot = sp + pself;

    float acc = acc0 + acc1;
    float v = (lane < 40) ? (acc / stot + b2[lane]) : -INFINITY;
    float mx = v;
    for (int st = 1; st < 64; st <<= 1) mx = fmaxf(mx, __shfl_xor(mx, st));
    float ex = (lane < 40) ? __expf(v - mx) : 0.f;
    float se = ex;
    for (int st = 1; st < 64; st <<= 1) se += __shfl_xor(se, st);
    if (lane < 40) out[(size_t)n * 40 + lane] = v - mx - logf(se);
}

extern "C" void kernel_launch(void* const* d_in, const int* in_sizes, int n_in,
                              void* d_out, int out_size, void* d_ws, size_t ws_size,
                              hipStream_t stream) {
    const float* x        = (const float*)d_in[0];
    const int*   ei       = (const int*)d_in[1];
    const float* W1       = (const float*)d_in[2];
    const float* att_src1 = (const float*)d_in[3];
    const float* att_dst1 = (const float*)d_in[4];
    const float* b1       = (const float*)d_in[5];
    const float* W2       = (const float*)d_in[6];
    const float* att_src2 = (const float*)d_in[7];
    const float* att_dst2 = (const float*)d_in[8];
    const float* b2       = (const float*)d_in[9];
    float* out = (float*)d_out;

    int N = in_sizes[0] / 128;
    int E = in_sizes[1] / 2;
    const int* src = ei;
    const int* dst = ei + E;
    int nbuck = (N + 127) >> 7;

    char* w = (char*)d_ws;
    auto alloc = [&](size_t bytes) { void* p = (void*)w; w += (bytes + 255) & ~(size_t)255; return p; };
    unsigned short* h1   = (unsigned short*)alloc((size_t)N * 64 * 2);
    unsigned short* helu = (unsigned short*)alloc((size_t)N * 64 * 2);
    float* as1  = (float*)alloc((size_t)N * 8 * 4);
    float* ad1  = (float*)alloc((size_t)N * 8 * 4);
    int*   degv = (int*)alloc((size_t)N * 4);
    int*   offv = (int*)alloc((size_t)(N + 1) * 4);
    int*   csr  = (int*)alloc((size_t)E * 4);
    int*   histG  = (int*)alloc((size_t)nbuck * GCHUNK * 4);
    int*   startG = (int*)alloc((size_t)nbuck * GCHUNK * 4);
    int*   total  = (int*)alloc((size_t)nbuck * 4);
    int*   bbase  = (int*)alloc((size_t)(nbuck + 1) * 4);
    int*   pairbuf = (int*)alloc((size_t)E * 4);
    unsigned short* h2p = h1;   // N*64 bf16, same size as h1 (dead after agg1)
    float* as2 = as1;
    float* ad2 = ad1;

    hipMemsetAsync(total, 0, (size_t)nbuck * 4, stream);
    hist_kernel<<<GCHUNK, 256, 0, stream>>>(dst, E, nbuck, histG, total);
    bscan_kernel<<<1, 1024, 0, stream>>>(total, bbase, nbuck);
    bstart_kernel<<<nbuck, 256, 0, stream>>>(histG, bbase, startG, nbuck);
    bucket_scatter<<<GCHUNK, 256, 0, stream>>>(src, dst, E, nbuck, startG, pairbuf);
    bucket_place<<<nbuck, 256, 0, stream>>>(pairbuf, bbase, nbuck, N, degv, offv, csr);

    int gb = (N + 127) / 128;
    gemm1_mfma<<<gb, 256, 0, stream>>>(x, W1, att_src1, att_dst1, h1, as1, ad1, N);
    agg1_kernel<<<(N + 3) / 4, 256, 0, stream>>>(h1, as1, ad1, offv, degv, csr, b1, helu, N);
    gemm2_mfma<<<gb, 256, 0, stream>>>(helu, W2, att_src2, att_dst2, h2p, as2, ad2, N);
    agg2_kernel<<<(N + 3) / 4, 256, 0, stream>>>(h2p, as2, ad2, offv, degv, csr, b2, out, N);
}